// Round 1
// baseline (322.489 us; speedup 1.0000x reference)
//
#include <hip/hip_runtime.h>
#include <stdint.h>

#define HH 16
#define DHD 64
#define BB 2
#define NN 2048
#define DD 1024
#define MMOD 4
#define LMAX 256
#define BNROWS (BB*NN)      // 4096
#define QKVN (3*HH*DHD)     // 3072

typedef __attribute__((ext_vector_type(4))) float f32x4;
typedef __attribute__((ext_vector_type(8))) short s16x8;

__device__ __forceinline__ float bf2f(unsigned short b) {
  return __uint_as_float(((unsigned int)b) << 16);
}
__device__ __forceinline__ unsigned short f2bf(float f) {
  unsigned int u = __float_as_uint(f);
  u += 0x7fffu + ((u >> 16) & 1u);
  return (unsigned short)(u >> 16);
}

#define ASYNC_LDS16(g, l) \
  __builtin_amdgcn_global_load_lds((const __attribute__((address_space(1))) void*)(g), \
                                   (__attribute__((address_space(3))) void*)(l), 16, 0, 0)

// ---------------------------------------------------------------------------
// K1: modality splice + norm + gamma, write xn bf16 [4096][1024]
// ---------------------------------------------------------------------------
__global__ __launch_bounds__(256) void k_prep(const float* __restrict__ x,
                                              const float* __restrict__ tokens,
                                              const float* __restrict__ gamma,
                                              const int* __restrict__ mods,
                                              unsigned short* __restrict__ xn) {
  int bs = blockIdx.x;
  int bb = bs / NN, s = bs % NN;
  int t = threadIdx.x;
  int c = t * 4;
  const float4 xv = *(const float4*)(x + (size_t)bs * DD + c);
  float4 acc = {0.f, 0.f, 0.f, 0.f};
  bool any = false;
  #pragma unroll
  for (int m = 0; m < MMOD; ++m) {
    int off = mods[(bb * MMOD + m) * 3 + 1];
    int ln  = mods[(bb * MMOD + m) * 3 + 2];
    if (s >= off && s < off + ln) {
      any = true;
      int rel = s - off;
      if (rel > LMAX - 1) rel = LMAX - 1;
      if (rel < 0) rel = 0;
      const float4 tv = *(const float4*)(tokens + ((size_t)(bb * MMOD + m) * LMAX + rel) * DD + c);
      acc.x += tv.x; acc.y += tv.y; acc.z += tv.z; acc.w += tv.w;
    }
  }
  float4 v = any ? acc : xv;
  float ss = v.x*v.x + v.y*v.y + v.z*v.z + v.w*v.w;
  #pragma unroll
  for (int o = 32; o; o >>= 1) ss += __shfl_xor(ss, o);
  __shared__ float red[4];
  int wv = t >> 6;
  if ((t & 63) == 0) red[wv] = ss;
  __syncthreads();
  float tot = red[0] + red[1] + red[2] + red[3];
  float norm = sqrtf(tot);
  norm = fmaxf(norm, 1e-12f);
  float sc = 32.0f / norm;   // sqrt(1024) = 32
  const float4 g = *(const float4*)(gamma + c);
  unsigned long long pk =
      (unsigned long long)f2bf(v.x * sc * (g.x + 1.f)) |
      ((unsigned long long)f2bf(v.y * sc * (g.y + 1.f)) << 16) |
      ((unsigned long long)f2bf(v.z * sc * (g.z + 1.f)) << 32) |
      ((unsigned long long)f2bf(v.w * sc * (g.w + 1.f)) << 48);
  *(unsigned long long*)(xn + (size_t)bs * DD + c) = pk;
}

// ---------------------------------------------------------------------------
// K2: pos[b][n] = s - cumsum(rot_any). One wave per batch.
// ---------------------------------------------------------------------------
__global__ void k_pos(const int* __restrict__ mods, int* __restrict__ pos) {
  int bb = blockIdx.x;
  int lane = threadIdx.x;       // 64
  int offs[MMOD], ends[MMOD];
  #pragma unroll
  for (int m = 0; m < MMOD; ++m) {
    int off = mods[(bb * MMOD + m) * 3 + 1];
    int ln  = mods[(bb * MMOD + m) * 3 + 2];
    offs[m] = off + 1;
    ends[m] = off + ln;
  }
  int base = lane * (NN / 64);  // 32 per lane
  int lc[NN / 64];
  int tot = 0;
  #pragma unroll
  for (int i = 0; i < NN / 64; ++i) {
    int s = base + i;
    int f = 0;
    #pragma unroll
    for (int m = 0; m < MMOD; ++m)
      if (s >= offs[m] && s < ends[m]) f = 1;
    tot += f;
    lc[i] = tot;
  }
  int v = tot;
  #pragma unroll
  for (int o = 1; o < 64; o <<= 1) {
    int u = __shfl_up(v, o);
    if (lane >= o) v += u;
  }
  int excl = v - tot;
  #pragma unroll
  for (int i = 0; i < NN / 64; ++i)
    pos[bb * NN + base + i] = base + i - (excl + lc[i]);
}

// ---------------------------------------------------------------------------
// K2b: RoPE cos/sin table [b*n][32] float2
// ---------------------------------------------------------------------------
__global__ void k_tab(const int* __restrict__ pos, float2* __restrict__ tab) {
  int gid = blockIdx.x * 256 + threadIdx.x;   // b*n*32 = 131072
  int p = gid & 31;
  int bs = gid >> 5;
  float inv = expf(-((float)p / 32.f) * 9.210340371976184f); // 1/10000^(2p/64)
  float ang = (float)pos[bs] * inv;
  float sn, cs;
  sincosf(ang, &sn, &cs);
  tab[gid] = make_float2(cs, sn);
}

// ---------------------------------------------------------------------------
// K3: transpose f32 [R][C] -> bf16 [C][R]
// ---------------------------------------------------------------------------
__global__ void k_tr(const float* __restrict__ in, unsigned short* __restrict__ out,
                     int R, int C) {
  __shared__ float tile[32][33];
  int bx = blockIdx.x, by = blockIdx.y;
  int tx = threadIdx.x, ty = threadIdx.y;
  #pragma unroll
  for (int k = 0; k < 4; ++k) {
    int r = by * 32 + ty + k * 8, c = bx * 32 + tx;
    tile[ty + k * 8][tx] = in[(size_t)r * C + c];
  }
  __syncthreads();
  #pragma unroll
  for (int k = 0; k < 4; ++k) {
    int oc = bx * 32 + ty + k * 8;
    int orr = by * 32 + tx;
    out[(size_t)oc * R + orr] = f2bf(tile[tx][ty + k * 8]);
  }
}

// ---------------------------------------------------------------------------
// K4/K7: GEMM  C[M][Nn] = A[M][K](bf16) * Bt[Nn][K](bf16)^T
// 128x128 tile, BK=64, 4 waves (2x2), 16x16x32 MFMA, global_load_lds staging.
// ---------------------------------------------------------------------------
template<bool F32OUT>
__global__ __launch_bounds__(256) void k_gemm(const unsigned short* __restrict__ A,
                                              const unsigned short* __restrict__ Bt,
                                              void* __restrict__ Cp,
                                              int M, int Nn, int K) {
  __shared__ unsigned short As[128 * 64];
  __shared__ unsigned short Bs[128 * 64];
  int tid = threadIdx.x;
  int lane = tid & 63, wv = tid >> 6;
  int m0 = blockIdx.y * 128, n0 = blockIdx.x * 128;
  int wr = wv >> 1, wc = wv & 1;
  f32x4 acc[4][4] = {};

  for (int kt = 0; kt < K; kt += 64) {
    __syncthreads();
    #pragma unroll
    for (int is = 0; is < 4; ++is) {
      int li = is * 256 + tid;
      int r = li >> 3, cc = (li & 7) * 8;
      const unsigned short* ga = A  + (size_t)(m0 + r) * K + kt + cc;
      const unsigned short* gb = Bt + (size_t)(n0 + r) * K + kt + cc;
      unsigned short* la = &As[(is * 256 + wv * 64) * 8];
      unsigned short* lb = &Bs[(is * 256 + wv * 64) * 8];
      ASYNC_LDS16(ga, la);
      ASYNC_LDS16(gb, lb);
    }
    __syncthreads();
    #pragma unroll
    for (int ks = 0; ks < 2; ++ks) {
      int ko = ks * 32 + ((lane >> 4) * 8);
      s16x8 af[4], bfr[4];
      #pragma unroll
      for (int m = 0; m < 4; ++m)
        af[m] = *(const s16x8*)&As[(wr * 64 + m * 16 + (lane & 15)) * 64 + ko];
      #pragma unroll
      for (int nn = 0; nn < 4; ++nn)
        bfr[nn] = *(const s16x8*)&Bs[(wc * 64 + nn * 16 + (lane & 15)) * 64 + ko];
      #pragma unroll
      for (int m = 0; m < 4; ++m)
        #pragma unroll
        for (int nn = 0; nn < 4; ++nn)
          acc[m][nn] = __builtin_amdgcn_mfma_f32_16x16x32_bf16(af[m], bfr[nn], acc[m][nn], 0, 0, 0);
    }
  }

  #pragma unroll
  for (int m = 0; m < 4; ++m) {
    #pragma unroll
    for (int nn = 0; nn < 4; ++nn) {
      int r0 = m0 + wr * 64 + m * 16 + ((lane >> 4) * 4);
      int cc = n0 + wc * 64 + nn * 16 + (lane & 15);
      #pragma unroll
      for (int j = 0; j < 4; ++j) {
        float val = acc[m][nn][j];
        if (F32OUT) ((float*)Cp)[(size_t)(r0 + j) * Nn + cc] = val;
        else        ((unsigned short*)Cp)[(size_t)(r0 + j) * Nn + cc] = f2bf(val);
      }
    }
  }
}

// ---------------------------------------------------------------------------
// K5: RoPE apply + reshape qkv_tmp[4096][3072] -> q/k/v [b*H][n][64] bf16
// ---------------------------------------------------------------------------
__global__ __launch_bounds__(256) void k_rope(const unsigned short* __restrict__ qkv,
                                              const float2* __restrict__ tab,
                                              unsigned short* __restrict__ q,
                                              unsigned short* __restrict__ k,
                                              unsigned short* __restrict__ v) {
  int bs = blockIdx.x;
  int bb = bs / NN, s = bs % NN;
  int lane = threadIdx.x & 63, wv = threadIdx.x >> 6;
  for (int g = wv; g < 48; g += 4) {
    int i3 = g >> 4, h = g & 15;
    float val = bf2f(qkv[(size_t)bs * QKVN + g * 64 + lane]);
    float out;
    if (i3 == 2) {
      out = val;
    } else {
      float partner = __shfl_xor(val, 1);
      float2 cs = tab[(size_t)bs * 32 + (lane >> 1)];
      if ((lane & 1) == 0) out = val * cs.x - partner * cs.y;      // t1*cos - t2*sin
      else                 out = partner * cs.y + val * cs.x;      // t1*sin + t2*cos
    }
    unsigned short* dst = (i3 == 0) ? q : (i3 == 1) ? k : v;
    dst[((size_t)(bb * HH + h) * NN + s) * 64 + lane] = f2bf(out);
  }
}

// ---------------------------------------------------------------------------
// K6: flash attention with row-wise key limit + tanh softcap
// grid (n/64, b*H), 4 waves; wave w handles q rows [q0+16w, q0+16w+16)
// ---------------------------------------------------------------------------
__global__ __launch_bounds__(256) void k_attn(const unsigned short* __restrict__ q,
                                              const unsigned short* __restrict__ k,
                                              const unsigned short* __restrict__ v,
                                              const int* __restrict__ mods,
                                              unsigned short* __restrict__ o) {
  __shared__ unsigned short Vt[64][72];       // [dh][key], stride 144B (16B aligned, 2-way banks)
  __shared__ unsigned short Pw[4][16][72];    // per-wave P [qrow][key]
  int tid = threadIdx.x;
  int lane = tid & 63, wv = tid >> 6;
  int bh = blockIdx.y;
  int bb = bh >> 4;
  int q0 = blockIdx.x * 64;
  const unsigned short* qb = q + (size_t)bh * NN * 64;
  const unsigned short* kb = k + (size_t)bh * NN * 64;
  const unsigned short* vb = v + (size_t)bh * NN * 64;

  s16x8 qf[2];
  {
    int qrow = q0 + wv * 16 + (lane & 15);
    #pragma unroll
    for (int ks = 0; ks < 2; ++ks)
      qf[ks] = *(const s16x8*)&qb[(size_t)qrow * 64 + ks * 32 + ((lane >> 4) * 8)];
  }

  int off_[MMOD], end_[MMOD];
  #pragma unroll
  for (int m = 0; m < MMOD; ++m) {
    off_[m] = mods[(bb * MMOD + m) * 3 + 1];
    end_[m] = off_[m] + mods[(bb * MMOD + m) * 3 + 2];
  }
  int limit[4];
  #pragma unroll
  for (int j = 0; j < 4; ++j) {
    int r = q0 + wv * 16 + ((lane >> 4) * 4) + j;
    int L = r + 1;
    #pragma unroll
    for (int m = 0; m < MMOD; ++m)
      if (off_[m] <= r && end_[m] > L) L = end_[m];
    limit[j] = L;
  }
  int kvmax = q0 + 64;
  {
    int rlast = q0 + 63;
    #pragma unroll
    for (int m = 0; m < MMOD; ++m)
      if (off_[m] <= rlast && end_[m] > kvmax) kvmax = end_[m];
    if (kvmax > NN) kvmax = NN;
  }

  float mrun[4] = {-1e30f, -1e30f, -1e30f, -1e30f};
  float lrun[4] = {0.f, 0.f, 0.f, 0.f};
  f32x4 accO[4] = {};

  for (int kv0 = 0; kv0 < kvmax; kv0 += 64) {
    __syncthreads();
    // stage V transposed
    #pragma unroll
    for (int it = 0; it < 2; ++it) {
      int idx = it * 256 + tid;         // 0..511
      int key = idx >> 3, cc = (idx & 7) * 8;
      s16x8 vvv = *(const s16x8*)&vb[(size_t)(kv0 + key) * 64 + cc];
      #pragma unroll
      for (int e = 0; e < 8; ++e)
        Vt[cc + e][key] = (unsigned short)vvv[e];
    }
    __syncthreads();

    // S = Q K^T for 4 column blocks of 16 keys
    f32x4 sv[4];
    #pragma unroll
    for (int cb = 0; cb < 4; ++cb) {
      size_t krow = (size_t)(kv0 + cb * 16 + (lane & 15)) * 64 + ((lane >> 4) * 8);
      s16x8 kf0 = *(const s16x8*)&kb[krow];
      s16x8 kf1 = *(const s16x8*)&kb[krow + 32];
      f32x4 z = {};
      z = __builtin_amdgcn_mfma_f32_16x16x32_bf16(qf[0], kf0, z, 0, 0, 0);
      z = __builtin_amdgcn_mfma_f32_16x16x32_bf16(qf[1], kf1, z, 0, 0, 0);
      sv[cb] = z;
    }

    // softcap + mask + online softmax
    float pm[4][4];
    float tmax[4] = {-1e30f, -1e30f, -1e30f, -1e30f};
    #pragma unroll
    for (int cb = 0; cb < 4; ++cb) {
      int col = kv0 + cb * 16 + (lane & 15);
      #pragma unroll
      for (int j = 0; j < 4; ++j) {
        float val = sv[cb][j] * 0.125f;           // 1/sqrt(64)
        float xx = val * 0.02f;                   // /50
        xx = fminf(fmaxf(xx, -15.f), 15.f);
        float e2 = __expf(2.f * xx);
        val = 50.f * ((e2 - 1.f) / (e2 + 1.f));
        if (col >= limit[j]) val = -1e30f;
        pm[cb][j] = val;
        if (val > tmax[j]) tmax[j] = val;
      }
    }
    #pragma unroll
    for (int o2 = 1; o2 < 16; o2 <<= 1)
      #pragma unroll
      for (int j = 0; j < 4; ++j) {
        float t = __shfl_xor(tmax[j], o2);
        if (t > tmax[j]) tmax[j] = t;
      }
    float corr[4];
    #pragma unroll
    for (int j = 0; j < 4; ++j) {
      float mn = fmaxf(mrun[j], tmax[j]);
      corr[j] = __expf(mrun[j] - mn);
      mrun[j] = mn;
    }
    float rsum[4] = {0.f, 0.f, 0.f, 0.f};
    #pragma unroll
    for (int cb = 0; cb < 4; ++cb)
      #pragma unroll
      for (int j = 0; j < 4; ++j) {
        float p = __expf(pm[cb][j] - mrun[j]);
        pm[cb][j] = p;
        rsum[j] += p;
      }
    #pragma unroll
    for (int o2 = 1; o2 < 16; o2 <<= 1)
      #pragma unroll
      for (int j = 0; j < 4; ++j) rsum[j] += __shfl_xor(rsum[j], o2);
    #pragma unroll
    for (int j = 0; j < 4; ++j) lrun[j] = lrun[j] * corr[j] + rsum[j];
    #pragma unroll
    for (int cb = 0; cb < 4; ++cb)
      #pragma unroll
      for (int j = 0; j < 4; ++j) accO[cb][j] *= corr[j];

    // P -> LDS (bf16), then PV
    #pragma unroll
    for (int cb = 0; cb < 4; ++cb)
      #pragma unroll
      for (int j = 0; j < 4; ++j)
        Pw[wv][((lane >> 4) * 4) + j][cb * 16 + (lane & 15)] = f2bf(pm[cb][j]);

    #pragma unroll
    for (int ks = 0; ks < 2; ++ks) {
      s16x8 pa = *(const s16x8*)&Pw[wv][lane & 15][ks * 32 + ((lane >> 4) * 8)];
      #pragma unroll
      for (int cb = 0; cb < 4; ++cb) {
        s16x8 vf = *(const s16x8*)&Vt[cb * 16 + (lane & 15)][ks * 32 + ((lane >> 4) * 8)];
        accO[cb] = __builtin_amdgcn_mfma_f32_16x16x32_bf16(pa, vf, accO[cb], 0, 0, 0);
      }
    }
  }

  int h = bh & 15;
  #pragma unroll
  for (int cb = 0; cb < 4; ++cb)
    #pragma unroll
    for (int j = 0; j < 4; ++j) {
      int r = q0 + wv * 16 + ((lane >> 4) * 4) + j;
      float val = accO[cb][j] / lrun[j];
      o[((size_t)(bb * NN) + r) * (HH * DHD) + h * 64 + cb * 16 + (lane & 15)] = f2bf(val);
    }
}

// ---------------------------------------------------------------------------
extern "C" void kernel_launch(void* const* d_in, const int* in_sizes, int n_in,
                              void* d_out, int out_size, void* d_ws, size_t ws_size,
                              hipStream_t stream) {
  (void)in_sizes; (void)n_in; (void)out_size; (void)ws_size;
  const float* x      = (const float*)d_in[0];
  const float* tokens = (const float*)d_in[1];
  const float* gamma  = (const float*)d_in[2];
  const float* w_qkv  = (const float*)d_in[3];
  const float* w_out  = (const float*)d_in[4];
  const int*   mods   = (const int*)d_in[5];

  char* ws = (char*)d_ws;
  unsigned short* xn    = (unsigned short*)(ws + 0);           //  8 MB
  unsigned short* wqkvT = (unsigned short*)(ws + 8388608);     //  6 MB
  unsigned short* woutT = (unsigned short*)(ws + 14680064);    //  2 MB
  unsigned short* qkvt  = (unsigned short*)(ws + 16777216);    // 24 MB
  unsigned short* qd    = (unsigned short*)(ws + 41943040);    //  8 MB
  unsigned short* kd    = (unsigned short*)(ws + 50331648);    //  8 MB
  unsigned short* vd    = (unsigned short*)(ws + 58720256);    //  8 MB
  unsigned short* attno = (unsigned short*)(ws + 67108864);    //  8 MB
  int*            pos   = (int*)(ws + 75497472);               // 16 KB
  float2*         tab   = (float2*)(ws + 75513856);            //  1 MB

  k_prep<<<BNROWS, 256, 0, stream>>>(x, tokens, gamma, mods, xn);
  k_pos<<<BB, 64, 0, stream>>>(mods, pos);
  k_tab<<<(BB * NN * 32) / 256, 256, 0, stream>>>(pos, tab);
  k_tr<<<dim3(QKVN / 32, DD / 32), dim3(32, 8), 0, stream>>>(w_qkv, wqkvT, DD, QKVN);
  k_tr<<<dim3((HH * DHD) / 32, DD / 32), dim3(32, 8), 0, stream>>>(w_out, woutT, HH * DHD, DD);
  k_gemm<false><<<dim3(QKVN / 128, BNROWS / 128), 256, 0, stream>>>(xn, wqkvT, (void*)qkvt, BNROWS, QKVN, DD);
  k_rope<<<BNROWS, 256, 0, stream>>>(qkvt, tab, qd, kd, vd);
  k_attn<<<dim3(NN / 64, BB * HH), 256, 0, stream>>>(qd, kd, vd, mods, attno);
  k_gemm<true><<<dim3(DD / 128, BNROWS / 128), 256, 0, stream>>>(attno, woutT, d_out, BNROWS, DD, DD);
}